// Round 13
// baseline (469.581 us; speedup 1.0000x reference)
//
#include <hip/hip_runtime.h>

typedef _Float16 f16x8 __attribute__((ext_vector_type(8)));
typedef _Float16 f16x4 __attribute__((ext_vector_type(4)));
typedef float    f32x4 __attribute__((ext_vector_type(4)));

#define BN    64           // points per block
#define KPAD  288          // padded K width for the skip layer
#define ROWB  (KPAD * 2)   // 576 bytes per LDS row
#define WELE  270336       // fp16 elements per weight bank (hi or lo)
#define LDS_ACT (2 * BN * ROWB)       // 73728 B activation buffers
#define LDS_TOTAL (LDS_ACT + 4096)    // + 4 layer biases ([4][256] f32)

// sched_group_barrier masks (LLVM SchedGroupMask)
#define SGB(mask, n) __builtin_amdgcn_sched_group_barrier((mask), (n), 0)
#define SG_MFMA   0x8
#define SG_VMEM_R 0x20
#define SG_DS_R   0x100

// XOR swizzle on the 16B-slot index for cols 0..255 (bytes 0..511).
__device__ __forceinline__ int swz(int row, int colb) {
  int c = (colb < 512) ? (colb ^ ((row & 7) << 4)) : colb;
  return row * ROWB + c;
}

__device__ __forceinline__ float gabor_f(float lin) {
  float a = 10.f * lin;                 // OMEGA == SIGMA == 10
  return __cosf(a) * __expf(-a * a);
}

// One 256-out gabor layer, split-precision weights in packed per-wave layout,
// software-pipelined 1 kk ahead on BOTH streams (W: global, B: LDS) with
// sched_group_barrier pinning per-iteration emission to
// {4 VMEM_READ, 4 DS_READ, 16 MFMA}. kk indices are compile-time (fully
// unrolled, no phase rotation) so W addresses fold to SGPR base + immediate.
template <int KS>
__device__ __forceinline__ void mfma_layer(const char* __restrict__ inb,
                                           char* __restrict__ outb,
                                           const _Float16* __restrict__ Wh,
                                           const _Float16* __restrict__ Wl,
                                           const float* __restrict__ lbias,
                                           int lane, int wid) {
  const int r = lane & 15;
  const int g = lane >> 4;
  const int n0 = wid * 32;
  f32x4 acc[2][4];
#pragma unroll
  for (int i = 0; i < 2; i++)
#pragma unroll
    for (int j = 0; j < 4; j++) {
      f32x4 z = {0.f, 0.f, 0.f, 0.f};
      acc[i][j] = z;
    }

  // ping-pong operand sets (fully unrolled loop -> static indices only)
  f16x8 a0[2], a1[2], c0[2], c1[2], b[2][4];

  // prologue: issue kk=0's W loads + B reads into set 0
  {
    const int wof = (wid * KS) * 1024 + lane * 8;
    a0[0] = *(const f16x8*)(Wh + wof);
    a1[0] = *(const f16x8*)(Wh + wof + 512);
    c0[0] = *(const f16x8*)(Wl + wof);
    c1[0] = *(const f16x8*)(Wl + wof + 512);
    const int kb = g * 8;
#pragma unroll
    for (int j = 0; j < 4; j++)
      b[0][j] = *(const f16x8*)(inb + swz(j * 16 + r, kb * 2));
    SGB(SG_VMEM_R, 4);
    SGB(SG_DS_R, 4);
  }

#pragma unroll
  for (int kk = 0; kk < KS; kk++) {
    const int cur = kk & 1;
    const int nxt = cur ^ 1;

    if (kk + 1 < KS) {                  // prefetch kk+1 (both streams)
      const int wof = (wid * KS + kk + 1) * 1024 + lane * 8;
      a0[nxt] = *(const f16x8*)(Wh + wof);
      a1[nxt] = *(const f16x8*)(Wh + wof + 512);
      c0[nxt] = *(const f16x8*)(Wl + wof);
      c1[nxt] = *(const f16x8*)(Wl + wof + 512);
      const int kb = (kk + 1) * 32 + g * 8;
#pragma unroll
      for (int j = 0; j < 4; j++)
        b[nxt][j] = *(const f16x8*)(inb + swz(j * 16 + r, kb * 2));
    }

    acc[0][0] = __builtin_amdgcn_mfma_f32_16x16x32_f16(a0[cur], b[cur][0], acc[0][0], 0, 0, 0);
    acc[0][1] = __builtin_amdgcn_mfma_f32_16x16x32_f16(a0[cur], b[cur][1], acc[0][1], 0, 0, 0);
    acc[0][2] = __builtin_amdgcn_mfma_f32_16x16x32_f16(a0[cur], b[cur][2], acc[0][2], 0, 0, 0);
    acc[0][3] = __builtin_amdgcn_mfma_f32_16x16x32_f16(a0[cur], b[cur][3], acc[0][3], 0, 0, 0);
    acc[1][0] = __builtin_amdgcn_mfma_f32_16x16x32_f16(a1[cur], b[cur][0], acc[1][0], 0, 0, 0);
    acc[1][1] = __builtin_amdgcn_mfma_f32_16x16x32_f16(a1[cur], b[cur][1], acc[1][1], 0, 0, 0);
    acc[1][2] = __builtin_amdgcn_mfma_f32_16x16x32_f16(a1[cur], b[cur][2], acc[1][2], 0, 0, 0);
    acc[1][3] = __builtin_amdgcn_mfma_f32_16x16x32_f16(a1[cur], b[cur][3], acc[1][3], 0, 0, 0);
    acc[0][0] = __builtin_amdgcn_mfma_f32_16x16x32_f16(c0[cur], b[cur][0], acc[0][0], 0, 0, 0);
    acc[0][1] = __builtin_amdgcn_mfma_f32_16x16x32_f16(c0[cur], b[cur][1], acc[0][1], 0, 0, 0);
    acc[0][2] = __builtin_amdgcn_mfma_f32_16x16x32_f16(c0[cur], b[cur][2], acc[0][2], 0, 0, 0);
    acc[0][3] = __builtin_amdgcn_mfma_f32_16x16x32_f16(c0[cur], b[cur][3], acc[0][3], 0, 0, 0);
    acc[1][0] = __builtin_amdgcn_mfma_f32_16x16x32_f16(c1[cur], b[cur][0], acc[1][0], 0, 0, 0);
    acc[1][1] = __builtin_amdgcn_mfma_f32_16x16x32_f16(c1[cur], b[cur][1], acc[1][1], 0, 0, 0);
    acc[1][2] = __builtin_amdgcn_mfma_f32_16x16x32_f16(c1[cur], b[cur][2], acc[1][2], 0, 0, 0);
    acc[1][3] = __builtin_amdgcn_mfma_f32_16x16x32_f16(c1[cur], b[cur][3], acc[1][3], 0, 0, 0);

    // pin this iteration's emission: prefetches first, then the MFMA cluster
    if (kk + 1 < KS) {
      SGB(SG_VMEM_R, 4);
      SGB(SG_DS_R, 4);
    }
    SGB(SG_MFMA, 16);
  }

  // epilogue: +bias (LDS), gabor, pack 4 consecutive units -> ds_write_b64
#pragma unroll
  for (int i = 0; i < 2; i++) {
    const f32x4 bv = *(const f32x4*)(lbias + n0 + i * 16 + g * 4);
#pragma unroll
    for (int j = 0; j < 4; j++) {
      f16x4 hv;
#pragma unroll
      for (int e = 0; e < 4; e++)
        hv[e] = (_Float16)gabor_f(acc[i][j][e] + bv[e]);
      *(f16x4*)(outb + swz(j * 16 + r, (n0 + i * 16 + g * 4) * 2)) = hv;
    }
  }
}

// NOTE: hipcc's __launch_bounds__ 2nd arg is min BLOCKS per CU (CUDA
// semantics). (512,4) forced 8 waves/SIMD -> 64-VGPR cap -> every pipeline
// attempt spilled. (512,2) = 2 blocks/CU = 4 waves/SIMD -> 128-VGPR budget,
// matching the LDS-bound occupancy exactly.
extern "C" __global__ void __launch_bounds__(512, 2)
inr_fused(const float* __restrict__ x, const float* __restrict__ W0,
          const float* __restrict__ b0, const float* __restrict__ b1,
          const float* __restrict__ b2, const float* __restrict__ b3,
          const float* __restrict__ b4, const float* __restrict__ Wf,
          const float* __restrict__ bf, const _Float16* __restrict__ wsh,
          float* __restrict__ out, int npts) {
  extern __shared__ char smem[];
  char* bufA = smem;
  char* bufB = smem + BN * ROWB;
  float* lbias = (float*)(smem + LDS_ACT);   // [4][256]

  // packed layer bases (halves): L1 @0, L2 @65536, L4 @131072, L3 @196608
  const _Float16* w1h = wsh;
  const _Float16* w2h = wsh + 65536;
  const _Float16* w4h = wsh + 131072;
  const _Float16* w3p = wsh + 196608;
  const _Float16* w1l = wsh + WELE;
  const _Float16* w2l = wsh + WELE + 65536;
  const _Float16* w4l = wsh + WELE + 131072;
  const _Float16* w3l = wsh + WELE + 196608;

  const int tid   = threadIdx.x;
  const int pbase = blockIdx.x * BN;

  // stage the 4 layer biases into LDS (epilogues then have NO vmem ops,
  // so they can't be absorbed into the SGB VMEM groups)
  if (tid < 256) {
    lbias[tid]       = b1[tid];
    lbias[256 + tid] = b2[tid];
    lbias[512 + tid] = b3[tid];
    lbias[768 + tid] = b4[tid];
  }

  // ---- layer 0: K=3 linear + gabor, fp32 VALU; also fill skip cols ----
  {
    const int p = tid >> 3;             // 64 points, 8 threads each
    const int q = tid & 7;              // each thread: 32 units
    const int gp = pbase + p;
    float x0 = 0.f, x1 = 0.f, x2 = 0.f;
    if (gp < npts) {
      x0 = x[(size_t)gp * 3 + 0];
      x1 = x[(size_t)gp * 3 + 1];
      x2 = x[(size_t)gp * 3 + 2];
    }
#pragma unroll
    for (int ub = 0; ub < 32; ub += 8) {
      const int u0 = q * 32 + ub;
      f16x8 hv;
#pragma unroll
      for (int e = 0; e < 8; e++) {
        const int u = u0 + e;
        float lin = fmaf(x0, W0[u * 3 + 0],
                    fmaf(x1, W0[u * 3 + 1],
                    fmaf(x2, W0[u * 3 + 2], b0[u])));
        hv[e] = (_Float16)gabor_f(lin);
      }
      *(f16x8*)(bufA + swz(p, u0 * 2)) = hv;
    }
    // skip-concat cols 256..287 of bufA: [x0,x1,x2, 0...0]
    if (q < 4) {
      f16x8 xv = {(_Float16)0.f, (_Float16)0.f, (_Float16)0.f, (_Float16)0.f,
                  (_Float16)0.f, (_Float16)0.f, (_Float16)0.f, (_Float16)0.f};
      if (q == 0) { xv[0] = (_Float16)x0; xv[1] = (_Float16)x1; xv[2] = (_Float16)x2; }
      *(f16x8*)(bufA + swz(p, (256 + q * 8) * 2)) = xv;
    }
  }
  __syncthreads();

  const int lane = tid & 63;
  const int wid  = tid >> 6;            // 8 waves: 8 unit-slices, all points

  mfma_layer<8>(bufA, bufB, w1h, w1l, lbias,       lane, wid);  // L1
  __syncthreads();
  mfma_layer<8>(bufB, bufA, w2h, w2l, lbias + 256, lane, wid);  // L2
  __syncthreads();
  mfma_layer<9>(bufA, bufB, w3p, w3l, lbias + 512, lane, wid);  // L3 (KS=9)
  __syncthreads();
  mfma_layer<8>(bufB, bufA, w4h, w4l, lbias + 768, lane, wid);  // L4
  __syncthreads();

  // ---- final linear: 3 outputs per point, fp32 VALU ----
  if (tid < BN * 3) {
    const int p = tid / 3;
    const int o = tid - p * 3;
    const int gp = pbase + p;
    if (gp < npts) {
      float a0 = bf[o], a1 = 0.f, a2 = 0.f, a3 = 0.f;
#pragma unroll 4
      for (int k = 0; k < 256; k += 8) {
        f16x8 hv = *(const f16x8*)(bufA + swz(p, k * 2));
        f32x4 wa = *(const f32x4*)(Wf + o * 256 + k);
        f32x4 wb = *(const f32x4*)(Wf + o * 256 + k + 4);
        a0 = fmaf((float)hv[0], wa[0], a0);
        a1 = fmaf((float)hv[1], wa[1], a1);
        a2 = fmaf((float)hv[2], wa[2], a2);
        a3 = fmaf((float)hv[3], wa[3], a3);
        a0 = fmaf((float)hv[4], wb[0], a0);
        a1 = fmaf((float)hv[5], wb[1], a1);
        a2 = fmaf((float)hv[6], wb[2], a2);
        a3 = fmaf((float)hv[7], wb[3], a3);
      }
      out[(size_t)gp * 3 + o] = (a0 + a1) + (a2 + a3);
    }
  }
}

// fp32 -> split fp16 (hi + lo residual) weight conversion, PACKED into the
// per-wave MFMA fragment order:
//   packed idx (within layer) = (((slice*KS + kk)*2 + i)*64 + lane)*8 + e
//   source: unit = slice*32 + i*16 + (lane&15); k = kk*32 + (lane>>4)*8 + e
// hi bank at [0, WELE), lo bank at [WELE, 2*WELE). Layer bases (halves):
//   L1 @0 (KS=8), L2 @65536 (KS=8), L4 @131072 (KS=8), L3 @196608 (KS=9,
//   K=288 zero-padded from 259).
extern "C" __global__ void conv_w(const float* __restrict__ W1,
                                  const float* __restrict__ W2,
                                  const float* __restrict__ W4,
                                  const float* __restrict__ W3,
                                  _Float16* __restrict__ wsh) {
  int idx = blockIdx.x * blockDim.x + threadIdx.x;
  if (idx >= WELE) return;

  int base, KS;
  const float* src = nullptr;
  int ldk = 256, kmax = 256;
  if (idx < 65536)       { base = 0;      KS = 8; src = W1; }
  else if (idx < 131072) { base = 65536;  KS = 8; src = W2; }
  else if (idx < 196608) { base = 131072; KS = 8; src = W4; }
  else                   { base = 196608; KS = 9; src = W3; ldk = 259; kmax = 259; }

  const int t    = idx - base;
  const int e    = t & 7;
  const int lane = (t >> 3) & 63;
  const int i    = (t >> 9) & 1;
  const int rem  = t >> 10;
  const int kk   = rem % KS;
  const int slice = rem / KS;

  const int unit = slice * 32 + i * 16 + (lane & 15);
  const int k    = kk * 32 + (lane >> 4) * 8 + e;

  const float w = (k < kmax) ? src[(size_t)unit * ldk + k] : 0.f;
  const _Float16 hi = (_Float16)w;
  const _Float16 lo = (_Float16)(w - (float)hi);
  wsh[idx] = hi;
  wsh[idx + WELE] = lo;
}

extern "C" void kernel_launch(void* const* d_in, const int* in_sizes, int n_in,
                              void* d_out, int out_size, void* d_ws, size_t ws_size,
                              hipStream_t stream) {
  const float* x  = (const float*)d_in[0];
  const float* W0 = (const float*)d_in[1];
  const float* b0 = (const float*)d_in[2];
  const float* W1 = (const float*)d_in[3];
  const float* b1 = (const float*)d_in[4];
  const float* W2 = (const float*)d_in[5];
  const float* b2 = (const float*)d_in[6];
  const float* W3 = (const float*)d_in[7];
  const float* b3 = (const float*)d_in[8];
  const float* W4 = (const float*)d_in[9];
  const float* b4 = (const float*)d_in[10];
  const float* Wf = (const float*)d_in[11];
  const float* bf = (const float*)d_in[12];
  float* out      = (float*)d_out;
  _Float16* wsh   = (_Float16*)d_ws;    // needs 2*WELE*2 B = 1081344 B

  const int npts = in_sizes[0] / 3;

  conv_w<<<(WELE + 511) / 512, 512, 0, stream>>>(W1, W2, W4, W3, wsh);

  const int nblk = (npts + BN - 1) / BN;
  inr_fused<<<nblk, 512, LDS_TOTAL, stream>>>(x, W0, b0, b1, b2, b3, b4,
                                              Wf, bf, wsh, out, npts);
}

// Round 14
// 440.274 us; speedup vs baseline: 1.0666x; 1.0666x over previous
//
#include <hip/hip_runtime.h>

typedef _Float16 f16x8 __attribute__((ext_vector_type(8)));
typedef _Float16 f16x4 __attribute__((ext_vector_type(4)));
typedef float    f32x4 __attribute__((ext_vector_type(4)));

#define BN    48           // points per block (3 blocks/CU: LDS = 52224 B)
#define ROWA  576          // bufA row bytes (288 cols: 256 units + skip x)
#define ROWB2 512          // bufB row bytes (256 unit cols only)
#define WELE  270336       // fp16 elements per weight bank (hi or lo)
#define LDS_TOTAL (BN * ROWA + BN * ROWB2)

// XOR swizzle on the 16B-slot index for cols 0..255 (bytes 0..511); bytes
// 512..575 (bufA's skip-x cols) stay linear. rb = row stride of the buffer.
__device__ __forceinline__ int swzr(int row, int colb, int rb) {
  int c = (colb < 512) ? (colb ^ ((row & 7) << 4)) : colb;
  return row * rb + c;
}

__device__ __forceinline__ float gabor_f(float lin) {
  float a = 10.f * lin;                 // OMEGA == SIGMA == 10
  return __cosf(a) * __expf(-a * a);
}

// One 256-out gabor layer, split-precision weights in packed per-wave layout
// (one sequential 1KB block per wave per kk per hi/lo half). Wave wid owns
// units [wid*32, wid*32+32) for all BN points. kk order rotated per block to
// de-sync the CUs' shared W stream in L2.
template <int KS, int RIN, int ROUT>
__device__ __forceinline__ void mfma_layer(const char* __restrict__ inb,
                                           char* __restrict__ outb,
                                           const _Float16* __restrict__ Wh,
                                           const _Float16* __restrict__ Wl,
                                           const float* __restrict__ bias,
                                           int lane, int wid, int phase) {
  const int r = lane & 15;
  const int g = lane >> 4;
  const int n0 = wid * 32;
  f32x4 acc[2][3];
#pragma unroll
  for (int i = 0; i < 2; i++)
#pragma unroll
    for (int j = 0; j < 3; j++) {
      f32x4 z = {0.f, 0.f, 0.f, 0.f};
      acc[i][j] = z;
    }

#pragma unroll
  for (int kk = 0; kk < KS; kk++) {
    int kkr = kk + phase;
    if (kkr >= KS) kkr -= KS;

    // packed W: (( (wid*KS+kkr)*2 + i )*64 + lane)*8 halves
    const int wof = (wid * KS + kkr) * 1024 + lane * 8;
    f16x8 a0 = *(const f16x8*)(Wh + wof);
    f16x8 a1 = *(const f16x8*)(Wh + wof + 512);
    f16x8 c0 = *(const f16x8*)(Wl + wof);
    f16x8 c1 = *(const f16x8*)(Wl + wof + 512);

    const int kb = kkr * 32 + g * 8;    // k element offset for this lane group
    f16x8 b0 = *(const f16x8*)(inb + swzr(0 * 16 + r, kb * 2, RIN));
    f16x8 b1 = *(const f16x8*)(inb + swzr(1 * 16 + r, kb * 2, RIN));
    f16x8 b2 = *(const f16x8*)(inb + swzr(2 * 16 + r, kb * 2, RIN));

    acc[0][0] = __builtin_amdgcn_mfma_f32_16x16x32_f16(a0, b0, acc[0][0], 0, 0, 0);
    acc[0][1] = __builtin_amdgcn_mfma_f32_16x16x32_f16(a0, b1, acc[0][1], 0, 0, 0);
    acc[0][2] = __builtin_amdgcn_mfma_f32_16x16x32_f16(a0, b2, acc[0][2], 0, 0, 0);
    acc[1][0] = __builtin_amdgcn_mfma_f32_16x16x32_f16(a1, b0, acc[1][0], 0, 0, 0);
    acc[1][1] = __builtin_amdgcn_mfma_f32_16x16x32_f16(a1, b1, acc[1][1], 0, 0, 0);
    acc[1][2] = __builtin_amdgcn_mfma_f32_16x16x32_f16(a1, b2, acc[1][2], 0, 0, 0);
    acc[0][0] = __builtin_amdgcn_mfma_f32_16x16x32_f16(c0, b0, acc[0][0], 0, 0, 0);
    acc[0][1] = __builtin_amdgcn_mfma_f32_16x16x32_f16(c0, b1, acc[0][1], 0, 0, 0);
    acc[0][2] = __builtin_amdgcn_mfma_f32_16x16x32_f16(c0, b2, acc[0][2], 0, 0, 0);
    acc[1][0] = __builtin_amdgcn_mfma_f32_16x16x32_f16(c1, b0, acc[1][0], 0, 0, 0);
    acc[1][1] = __builtin_amdgcn_mfma_f32_16x16x32_f16(c1, b1, acc[1][1], 0, 0, 0);
    acc[1][2] = __builtin_amdgcn_mfma_f32_16x16x32_f16(c1, b2, acc[1][2], 0, 0, 0);
  }

  // epilogue: +bias, gabor, pack 4 consecutive units -> one ds_write_b64
#pragma unroll
  for (int i = 0; i < 2; i++) {
    const f32x4 bv = *(const f32x4*)(bias + n0 + i * 16 + g * 4);
#pragma unroll
    for (int j = 0; j < 3; j++) {
      f16x4 hv;
#pragma unroll
      for (int e = 0; e < 4; e++)
        hv[e] = (_Float16)gabor_f(acc[i][j][e] + bv[e]);
      *(f16x4*)(outb + swzr(j * 16 + r, (n0 + i * 16 + g * 4) * 2, ROUT)) = hv;
    }
  }
}

extern "C" __global__ void __launch_bounds__(512, 3)
inr_fused(const float* __restrict__ x, const float* __restrict__ W0,
          const float* __restrict__ b0, const float* __restrict__ b1,
          const float* __restrict__ b2, const float* __restrict__ b3,
          const float* __restrict__ b4, const float* __restrict__ Wf,
          const float* __restrict__ bf, const _Float16* __restrict__ wsh,
          float* __restrict__ out, int npts) {
  extern __shared__ char smem[];
  char* bufA = smem;                    // [BN][576] (units + skip-x cols)
  char* bufB = smem + BN * ROWA;        // [BN][512] (units only)

  // packed layer bases (halves): L1 @0, L2 @65536, L4 @131072, L3 @196608
  const _Float16* w1h = wsh;
  const _Float16* w2h = wsh + 65536;
  const _Float16* w4h = wsh + 131072;
  const _Float16* w3p = wsh + 196608;
  const _Float16* w1l = wsh + WELE;
  const _Float16* w2l = wsh + WELE + 65536;
  const _Float16* w4l = wsh + WELE + 131072;
  const _Float16* w3l = wsh + WELE + 196608;

  const int tid   = threadIdx.x;
  const int pbase = blockIdx.x * BN;
  const int phase = blockIdx.x & 7;     // kk rotation (de-sync CUs in L2)

  // ---- layer 0: K=3 linear + gabor, fp32 VALU; also fill skip cols ----
  {
    const int p = tid >> 3;             // 8 threads per point
    const int q = tid & 7;              // each thread: 32 units
    if (p < BN) {
      const int gp = pbase + p;
      float x0 = 0.f, x1 = 0.f, x2 = 0.f;
      if (gp < npts) {
        x0 = x[(size_t)gp * 3 + 0];
        x1 = x[(size_t)gp * 3 + 1];
        x2 = x[(size_t)gp * 3 + 2];
      }
#pragma unroll
      for (int ub = 0; ub < 32; ub += 8) {
        const int u0 = q * 32 + ub;
        f16x8 hv;
#pragma unroll
        for (int e = 0; e < 8; e++) {
          const int u = u0 + e;
          float lin = fmaf(x0, W0[u * 3 + 0],
                      fmaf(x1, W0[u * 3 + 1],
                      fmaf(x2, W0[u * 3 + 2], b0[u])));
          hv[e] = (_Float16)gabor_f(lin);
        }
        *(f16x8*)(bufA + swzr(p, u0 * 2, ROWA)) = hv;
      }
      // skip-concat cols 256..287 of bufA: [x0,x1,x2, 0...0]
      if (q < 4) {
        f16x8 xv = {(_Float16)0.f, (_Float16)0.f, (_Float16)0.f, (_Float16)0.f,
                    (_Float16)0.f, (_Float16)0.f, (_Float16)0.f, (_Float16)0.f};
        if (q == 0) { xv[0] = (_Float16)x0; xv[1] = (_Float16)x1; xv[2] = (_Float16)x2; }
        *(f16x8*)(bufA + swzr(p, (256 + q * 8) * 2, ROWA)) = xv;
      }
    }
  }
  __syncthreads();

  const int lane = tid & 63;
  const int wid  = tid >> 6;            // 8 waves: 8 unit-slices, all points

  mfma_layer<8, ROWA, ROWB2>(bufA, bufB, w1h, w1l, b1, lane, wid, phase);  // L1
  __syncthreads();
  mfma_layer<8, ROWB2, ROWA>(bufB, bufA, w2h, w2l, b2, lane, wid, phase);  // L2
  __syncthreads();
  mfma_layer<9, ROWA, ROWB2>(bufA, bufB, w3p, w3l, b3, lane, wid, phase);  // L3 (K=288)
  __syncthreads();
  mfma_layer<8, ROWB2, ROWA>(bufB, bufA, w4h, w4l, b4, lane, wid, phase);  // L4
  __syncthreads();

  // ---- final linear: 3 outputs per point, fp32 VALU ----
  if (tid < BN * 3) {
    const int p = tid / 3;
    const int o = tid - p * 3;
    const int gp = pbase + p;
    if (gp < npts) {
      float a0 = bf[o], a1 = 0.f, a2 = 0.f, a3 = 0.f;
#pragma unroll 4
      for (int k = 0; k < 256; k += 8) {
        f16x8 hv = *(const f16x8*)(bufA + swzr(p, k * 2, ROWA));
        f32x4 wa = *(const f32x4*)(Wf + o * 256 + k);
        f32x4 wb = *(const f32x4*)(Wf + o * 256 + k + 4);
        a0 = fmaf((float)hv[0], wa[0], a0);
        a1 = fmaf((float)hv[1], wa[1], a1);
        a2 = fmaf((float)hv[2], wa[2], a2);
        a3 = fmaf((float)hv[3], wa[3], a3);
        a0 = fmaf((float)hv[4], wb[0], a0);
        a1 = fmaf((float)hv[5], wb[1], a1);
        a2 = fmaf((float)hv[6], wb[2], a2);
        a3 = fmaf((float)hv[7], wb[3], a3);
      }
      out[(size_t)gp * 3 + o] = (a0 + a1) + (a2 + a3);
    }
  }
}

// fp32 -> split fp16 (hi + lo residual) weight conversion, PACKED into the
// per-wave MFMA fragment order:
//   packed idx (within layer) = (((slice*KS + kk)*2 + i)*64 + lane)*8 + e
//   source: unit = slice*32 + i*16 + (lane&15); k = kk*32 + (lane>>4)*8 + e
// hi bank at [0, WELE), lo bank at [WELE, 2*WELE). Layer bases (halves):
//   L1 @0 (KS=8), L2 @65536 (KS=8), L4 @131072 (KS=8), L3 @196608 (KS=9,
//   K=288 zero-padded from 259).
extern "C" __global__ void conv_w(const float* __restrict__ W1,
                                  const float* __restrict__ W2,
                                  const float* __restrict__ W4,
                                  const float* __restrict__ W3,
                                  _Float16* __restrict__ wsh) {
  int idx = blockIdx.x * blockDim.x + threadIdx.x;
  if (idx >= WELE) return;

  int base, KS;
  const float* src = nullptr;
  int ldk = 256, kmax = 256;
  if (idx < 65536)       { base = 0;      KS = 8; src = W1; }
  else if (idx < 131072) { base = 65536;  KS = 8; src = W2; }
  else if (idx < 196608) { base = 131072; KS = 8; src = W4; }
  else                   { base = 196608; KS = 9; src = W3; ldk = 259; kmax = 259; }

  const int t    = idx - base;
  const int e    = t & 7;
  const int lane = (t >> 3) & 63;
  const int i    = (t >> 9) & 1;
  const int rem  = t >> 10;
  const int kk   = rem % KS;
  const int slice = rem / KS;

  const int unit = slice * 32 + i * 16 + (lane & 15);
  const int k    = kk * 32 + (lane >> 4) * 8 + e;

  const float w = (k < kmax) ? src[(size_t)unit * ldk + k] : 0.f;
  const _Float16 hi = (_Float16)w;
  const _Float16 lo = (_Float16)(w - (float)hi);
  wsh[idx] = hi;
  wsh[idx + WELE] = lo;
}

extern "C" void kernel_launch(void* const* d_in, const int* in_sizes, int n_in,
                              void* d_out, int out_size, void* d_ws, size_t ws_size,
                              hipStream_t stream) {
  const float* x  = (const float*)d_in[0];
  const float* W0 = (const float*)d_in[1];
  const float* b0 = (const float*)d_in[2];
  const float* W1 = (const float*)d_in[3];
  const float* b1 = (const float*)d_in[4];
  const float* W2 = (const float*)d_in[5];
  const float* b2 = (const float*)d_in[6];
  const float* W3 = (const float*)d_in[7];
  const float* b3 = (const float*)d_in[8];
  const float* W4 = (const float*)d_in[9];
  const float* b4 = (const float*)d_in[10];
  const float* Wf = (const float*)d_in[11];
  const float* bf = (const float*)d_in[12];
  float* out      = (float*)d_out;
  _Float16* wsh   = (_Float16*)d_ws;    // needs 2*WELE*2 B = 1081344 B

  const int npts = in_sizes[0] / 3;

  conv_w<<<(WELE + 511) / 512, 512, 0, stream>>>(W1, W2, W4, W3, wsh);

  const int nblk = (npts + BN - 1) / BN;
  inr_fused<<<nblk, 512, LDS_TOTAL, stream>>>(x, W0, b0, b1, b2, b3, b4,
                                              Wf, bf, wsh, out, npts);
}

// Round 15
// 415.344 us; speedup vs baseline: 1.1306x; 1.0600x over previous
//
#include <hip/hip_runtime.h>

typedef _Float16 f16x8 __attribute__((ext_vector_type(8)));
typedef _Float16 f16x4 __attribute__((ext_vector_type(4)));
typedef float    f32x4 __attribute__((ext_vector_type(4)));

#define BN    64           // points per block
#define KPAD  288          // padded K width for the skip layer
#define ROWB  (KPAD * 2)   // 576 bytes per LDS row
#define WELE  270336       // fp16 elements per weight bank (hi or lo)

// XOR swizzle on the 16B-slot index for cols 0..255 (bytes 0..511); bytes
// 512..575 (skip-x cols) linear. Used only outside the hot kk loop.
__device__ __forceinline__ int swz(int row, int colb) {
  int c = (colb < 512) ? (colb ^ ((row & 7) << 4)) : colb;
  return row * ROWB + c;
}

__device__ __forceinline__ float gabor_f(float lin) {
  float a = 10.f * lin;                 // OMEGA == SIGMA == 10
  return __cosf(a) * __expf(-a * a);
}

// One 256-out gabor layer, split-precision weights in packed per-wave layout
// (sequential 1KB stream per wave per kk per hi/lo half). Compile-time kk
// (no phase rotation) + algebraic swizzle split:
//   swz(row, kk*64+g*16) = row*ROWB + (((kk&1)*64 + g*16) ^ x) + (kk>>1)*128
// so all B-reads are ds_read_b128 from 8 precomputed bases + immediate.
template <int KS>
__device__ __forceinline__ void mfma_layer(const char* __restrict__ inb,
                                           char* __restrict__ outb,
                                           const _Float16* __restrict__ Wh,
                                           const _Float16* __restrict__ Wl,
                                           const float* __restrict__ bias,
                                           int lane, int wid) {
  const int r = lane & 15;
  const int g = lane >> 4;
  const int n0 = wid * 32;
  const int x = (r & 7) << 4;

  // 8 precomputed B-read base offsets (4 point-tiles x kk parity)
  int boff[4][2];
#pragma unroll
  for (int j = 0; j < 4; j++) {
    const int row = j * 16 + r;
    boff[j][0] = row * ROWB + ((g * 16) ^ x);
    boff[j][1] = row * ROWB + ((64 + g * 16) ^ x);
  }

  f32x4 acc[2][4];
#pragma unroll
  for (int i = 0; i < 2; i++)
#pragma unroll
    for (int j = 0; j < 4; j++) {
      f32x4 z = {0.f, 0.f, 0.f, 0.f};
      acc[i][j] = z;
    }

  const int wbase = (wid * KS) * 1024 + lane * 8;

#pragma unroll
  for (int kk = 0; kk < KS; kk++) {
    // packed W stream: hi row0, hi row1, lo row0, lo row1 (16B each)
    const int wof = wbase + kk * 1024;
    f16x8 a0 = *(const f16x8*)(Wh + wof);
    f16x8 a1 = *(const f16x8*)(Wh + wof + 512);
    f16x8 c0 = *(const f16x8*)(Wl + wof);
    f16x8 c1 = *(const f16x8*)(Wl + wof + 512);

    f16x8 b0, b1, b2, b3;
    if (kk < 8) {                        // swizzled region: base + immediate
      const int imm = (kk >> 1) * 128;
      b0 = *(const f16x8*)(inb + boff[0][kk & 1] + imm);
      b1 = *(const f16x8*)(inb + boff[1][kk & 1] + imm);
      b2 = *(const f16x8*)(inb + boff[2][kk & 1] + imm);
      b3 = *(const f16x8*)(inb + boff[3][kk & 1] + imm);
    } else {                             // KS==9 skip chunk: linear cols 512+
      const int lin0 = r * ROWB + 512 + g * 16;
      b0 = *(const f16x8*)(inb + lin0);
      b1 = *(const f16x8*)(inb + lin0 + 16 * ROWB);
      b2 = *(const f16x8*)(inb + lin0 + 32 * ROWB);
      b3 = *(const f16x8*)(inb + lin0 + 48 * ROWB);
    }

    acc[0][0] = __builtin_amdgcn_mfma_f32_16x16x32_f16(a0, b0, acc[0][0], 0, 0, 0);
    acc[0][1] = __builtin_amdgcn_mfma_f32_16x16x32_f16(a0, b1, acc[0][1], 0, 0, 0);
    acc[0][2] = __builtin_amdgcn_mfma_f32_16x16x32_f16(a0, b2, acc[0][2], 0, 0, 0);
    acc[0][3] = __builtin_amdgcn_mfma_f32_16x16x32_f16(a0, b3, acc[0][3], 0, 0, 0);
    acc[1][0] = __builtin_amdgcn_mfma_f32_16x16x32_f16(a1, b0, acc[1][0], 0, 0, 0);
    acc[1][1] = __builtin_amdgcn_mfma_f32_16x16x32_f16(a1, b1, acc[1][1], 0, 0, 0);
    acc[1][2] = __builtin_amdgcn_mfma_f32_16x16x32_f16(a1, b2, acc[1][2], 0, 0, 0);
    acc[1][3] = __builtin_amdgcn_mfma_f32_16x16x32_f16(a1, b3, acc[1][3], 0, 0, 0);
    acc[0][0] = __builtin_amdgcn_mfma_f32_16x16x32_f16(c0, b0, acc[0][0], 0, 0, 0);
    acc[0][1] = __builtin_amdgcn_mfma_f32_16x16x32_f16(c0, b1, acc[0][1], 0, 0, 0);
    acc[0][2] = __builtin_amdgcn_mfma_f32_16x16x32_f16(c0, b2, acc[0][2], 0, 0, 0);
    acc[0][3] = __builtin_amdgcn_mfma_f32_16x16x32_f16(c0, b3, acc[0][3], 0, 0, 0);
    acc[1][0] = __builtin_amdgcn_mfma_f32_16x16x32_f16(c1, b0, acc[1][0], 0, 0, 0);
    acc[1][1] = __builtin_amdgcn_mfma_f32_16x16x32_f16(c1, b1, acc[1][1], 0, 0, 0);
    acc[1][2] = __builtin_amdgcn_mfma_f32_16x16x32_f16(c1, b2, acc[1][2], 0, 0, 0);
    acc[1][3] = __builtin_amdgcn_mfma_f32_16x16x32_f16(c1, b3, acc[1][3], 0, 0, 0);
  }

  // epilogue: +bias, gabor, pack 4 consecutive units -> one ds_write_b64
#pragma unroll
  for (int i = 0; i < 2; i++) {
    const f32x4 bv = *(const f32x4*)(bias + n0 + i * 16 + g * 4);
#pragma unroll
    for (int j = 0; j < 4; j++) {
      f16x4 hv;
#pragma unroll
      for (int e = 0; e < 4; e++)
        hv[e] = (_Float16)gabor_f(acc[i][j][e] + bv[e]);
      *(f16x4*)(outb + swz(j * 16 + r, (n0 + i * 16 + g * 4) * 2)) = hv;
    }
  }
}

// launch_bounds: 2nd arg is blocks/CU on hipcc. 3 -> VGPR cap 84 (headroom
// for the base-offset regs); LDS (73728B) still limits residency to 2.
extern "C" __global__ void __launch_bounds__(512, 3)
inr_fused(const float* __restrict__ x, const float* __restrict__ W0,
          const float* __restrict__ b0, const float* __restrict__ b1,
          const float* __restrict__ b2, const float* __restrict__ b3,
          const float* __restrict__ b4, const float* __restrict__ Wf,
          const float* __restrict__ bf, const _Float16* __restrict__ wsh,
          float* __restrict__ out, int npts) {
  extern __shared__ char smem[];
  char* bufA = smem;
  char* bufB = smem + BN * ROWB;

  // packed layer bases (halves): L1 @0, L2 @65536, L4 @131072, L3 @196608
  const _Float16* w1h = wsh;
  const _Float16* w2h = wsh + 65536;
  const _Float16* w4h = wsh + 131072;
  const _Float16* w3p = wsh + 196608;
  const _Float16* w1l = wsh + WELE;
  const _Float16* w2l = wsh + WELE + 65536;
  const _Float16* w4l = wsh + WELE + 131072;
  const _Float16* w3l = wsh + WELE + 196608;

  const int tid   = threadIdx.x;
  const int pbase = blockIdx.x * BN;

  // ---- layer 0: K=3 linear + gabor, fp32 VALU; also fill skip cols ----
  {
    const int p = tid >> 3;             // 64 points, 8 threads each
    const int q = tid & 7;              // each thread: 32 units
    const int gp = pbase + p;
    float x0 = 0.f, x1 = 0.f, x2 = 0.f;
    if (gp < npts) {
      x0 = x[(size_t)gp * 3 + 0];
      x1 = x[(size_t)gp * 3 + 1];
      x2 = x[(size_t)gp * 3 + 2];
    }
#pragma unroll
    for (int ub = 0; ub < 32; ub += 8) {
      const int u0 = q * 32 + ub;
      f16x8 hv;
#pragma unroll
      for (int e = 0; e < 8; e++) {
        const int u = u0 + e;
        float lin = fmaf(x0, W0[u * 3 + 0],
                    fmaf(x1, W0[u * 3 + 1],
                    fmaf(x2, W0[u * 3 + 2], b0[u])));
        hv[e] = (_Float16)gabor_f(lin);
      }
      *(f16x8*)(bufA + swz(p, u0 * 2)) = hv;
    }
    // skip-concat cols 256..287 of bufA: [x0,x1,x2, 0...0]
    if (q < 4) {
      f16x8 xv = {(_Float16)0.f, (_Float16)0.f, (_Float16)0.f, (_Float16)0.f,
                  (_Float16)0.f, (_Float16)0.f, (_Float16)0.f, (_Float16)0.f};
      if (q == 0) { xv[0] = (_Float16)x0; xv[1] = (_Float16)x1; xv[2] = (_Float16)x2; }
      *(f16x8*)(bufA + swz(p, (256 + q * 8) * 2)) = xv;
    }
  }
  __syncthreads();

  const int lane = tid & 63;
  const int wid  = tid >> 6;            // 8 waves: 8 unit-slices, all points

  mfma_layer<8>(bufA, bufB, w1h, w1l, b1, lane, wid);   // L1: A -> B
  __syncthreads();
  mfma_layer<8>(bufB, bufA, w2h, w2l, b2, lane, wid);   // L2: B -> A
  __syncthreads();
  mfma_layer<9>(bufA, bufB, w3p, w3l, b3, lane, wid);   // L3: K=288
  __syncthreads();
  mfma_layer<8>(bufB, bufA, w4h, w4l, b4, lane, wid);   // L4: B -> A
  __syncthreads();

  // ---- final linear: all 512 threads, 8 threads/point, shuffle reduce ----
  {
    const int p = tid >> 3;             // point within block
    const int q = tid & 7;              // k-chunk (32 units)
    const int gp = pbase + p;
    const int xo = (p & 7) << 4;
    const char* rowp = bufA + p * ROWB;
    float s0 = 0.f, s1 = 0.f, s2 = 0.f;
#pragma unroll
    for (int i8 = 0; i8 < 4; i8++) {
      const int ke = q * 32 + i8 * 8;   // unit index base
      f16x8 hv = *(const f16x8*)(rowp + ((ke * 2) ^ xo));
      const f32x4 w0a = *(const f32x4*)(Wf + 0 * 256 + ke);
      const f32x4 w0b = *(const f32x4*)(Wf + 0 * 256 + ke + 4);
      const f32x4 w1a = *(const f32x4*)(Wf + 1 * 256 + ke);
      const f32x4 w1b = *(const f32x4*)(Wf + 1 * 256 + ke + 4);
      const f32x4 w2a = *(const f32x4*)(Wf + 2 * 256 + ke);
      const f32x4 w2b = *(const f32x4*)(Wf + 2 * 256 + ke + 4);
#pragma unroll
      for (int e = 0; e < 4; e++) {
        const float ha = (float)hv[e];
        const float hb = (float)hv[e + 4];
        s0 = fmaf(ha, w0a[e], fmaf(hb, w0b[e], s0));
        s1 = fmaf(ha, w1a[e], fmaf(hb, w1b[e], s1));
        s2 = fmaf(ha, w2a[e], fmaf(hb, w2b[e], s2));
      }
    }
#pragma unroll
    for (int m = 1; m < 8; m <<= 1) {
      s0 += __shfl_xor(s0, m, 64);
      s1 += __shfl_xor(s1, m, 64);
      s2 += __shfl_xor(s2, m, 64);
    }
    if (gp < npts && q < 3) {
      const float v = (q == 0) ? (s0 + bf[0]) : ((q == 1) ? (s1 + bf[1]) : (s2 + bf[2]));
      out[(size_t)gp * 3 + q] = v;
    }
  }
}

// fp32 -> split fp16 (hi + lo residual) weight conversion, PACKED into the
// per-wave MFMA fragment order:
//   packed idx (within layer) = (((slice*KS + kk)*2 + i)*64 + lane)*8 + e
//   source: unit = slice*32 + i*16 + (lane&15); k = kk*32 + (lane>>4)*8 + e
// hi bank at [0, WELE), lo bank at [WELE, 2*WELE). Layer bases (halves):
//   L1 @0 (KS=8), L2 @65536 (KS=8), L4 @131072 (KS=8), L3 @196608 (KS=9,
//   K=288 zero-padded from 259).
extern "C" __global__ void conv_w(const float* __restrict__ W1,
                                  const float* __restrict__ W2,
                                  const float* __restrict__ W4,
                                  const float* __restrict__ W3,
                                  _Float16* __restrict__ wsh) {
  int idx = blockIdx.x * blockDim.x + threadIdx.x;
  if (idx >= WELE) return;

  int base, KS;
  const float* src = nullptr;
  int ldk = 256, kmax = 256;
  if (idx < 65536)       { base = 0;      KS = 8; src = W1; }
  else if (idx < 131072) { base = 65536;  KS = 8; src = W2; }
  else if (idx < 196608) { base = 131072; KS = 8; src = W4; }
  else                   { base = 196608; KS = 9; src = W3; ldk = 259; kmax = 259; }

  const int t    = idx - base;
  const int e    = t & 7;
  const int lane = (t >> 3) & 63;
  const int i    = (t >> 9) & 1;
  const int rem  = t >> 10;
  const int kk   = rem % KS;
  const int slice = rem / KS;

  const int unit = slice * 32 + i * 16 + (lane & 15);
  const int k    = kk * 32 + (lane >> 4) * 8 + e;

  const float w = (k < kmax) ? src[(size_t)unit * ldk + k] : 0.f;
  const _Float16 hi = (_Float16)w;
  const _Float16 lo = (_Float16)(w - (float)hi);
  wsh[idx] = hi;
  wsh[idx + WELE] = lo;
}

extern "C" void kernel_launch(void* const* d_in, const int* in_sizes, int n_in,
                              void* d_out, int out_size, void* d_ws, size_t ws_size,
                              hipStream_t stream) {
  const float* x  = (const float*)d_in[0];
  const float* W0 = (const float*)d_in[1];
  const float* b0 = (const float*)d_in[2];
  const float* W1 = (const float*)d_in[3];
  const float* b1 = (const float*)d_in[4];
  const float* W2 = (const float*)d_in[5];
  const float* b2 = (const float*)d_in[6];
  const float* W3 = (const float*)d_in[7];
  const float* b3 = (const float*)d_in[8];
  const float* W4 = (const float*)d_in[9];
  const float* b4 = (const float*)d_in[10];
  const float* Wf = (const float*)d_in[11];
  const float* bf = (const float*)d_in[12];
  float* out      = (float*)d_out;
  _Float16* wsh   = (_Float16*)d_ws;    // needs 2*WELE*2 B = 1081344 B

  const int npts = in_sizes[0] / 3;

  conv_w<<<(WELE + 511) / 512, 512, 0, stream>>>(W1, W2, W4, W3, wsh);

  const int nblk = (npts + BN - 1) / BN;
  inr_fused<<<nblk, 512, 2 * BN * ROWB, stream>>>(x, W0, b0, b1, b2, b3, b4,
                                                  Wf, bf, wsh, out, npts);
}